// Round 7
// baseline (318.982 us; speedup 1.0000x reference)
//
#include <hip/hip_runtime.h>
#include <cmath>

// Shapes: B=4, V=8, D=64, N=16, H=32, W=32, GROUPS=4
// rotation tables: a = radians(-45*v); c = cos(a), s = sin(a)
#define FSQ 0.70710678118654752440f
__constant__ float CTAB[8] = {1.f,  FSQ, 0.f, -FSQ, -1.f, -FSQ, 0.f, FSQ};
__constant__ float STAB[8] = {0.f, -FSQ, -1.f, -FSQ,  0.f,  FSQ, 1.f, FSQ};

typedef float f4 __attribute__((ext_vector_type(4)));

// ---------------------------------------------------------------------------
// GroupNorm: 16 blocks = (b, group), 1024 threads. Wave-shuffle reduction.
// ---------------------------------------------------------------------------
__global__ __launch_bounds__(1024) void gn_kernel(const float* __restrict__ u,
                                                  const float* __restrict__ gw,
                                                  const float* __restrict__ gb,
                                                  float* __restrict__ up)
{
    int blk = blockIdx.x;            // b*4 + g
    int b = blk >> 2, g = blk & 3;
    int t = threadIdx.x;
    const float* src = u + ((size_t)(b * 64 + g * 16) << 10);   // 16384 floats
    float sum = 0.f, sq = 0.f;
    #pragma unroll
    for (int r = 0; r < 16; ++r) {
        float v = src[t + (r << 10)];
        sum += v; sq += v * v;
    }
    #pragma unroll
    for (int ofs = 32; ofs > 0; ofs >>= 1) {
        sum += __shfl_down(sum, ofs);
        sq  += __shfl_down(sq, ofs);
    }
    __shared__ float red[16], red2[16];
    int wv = t >> 6;
    if ((t & 63) == 0) { red[wv] = sum; red2[wv] = sq; }
    __syncthreads();
    float s_tot = 0.f, q_tot = 0.f;
    #pragma unroll
    for (int k = 0; k < 16; ++k) { s_tot += red[k]; q_tot += red2[k]; }
    float mu  = s_tot * (1.f / 16384.f);
    float var = q_tot * (1.f / 16384.f) - mu * mu;
    float rs  = rsqrtf(var + 1e-5f);

    float* pb = up + (size_t)(b * 64 + g * 16) * 1156;
    for (int k = t; k < 16 * 132; k += 1024) {
        int pl = k / 132, c = k - pl * 132;
        int idx;
        if (c < 34)       idx = c;                       // row 0
        else if (c < 68)  idx = 33 * 34 + (c - 34);      // row 33
        else if (c < 100) idx = (c - 68 + 1) * 34;       // col 0, rows 1..32
        else              idx = (c - 100 + 1) * 34 + 33; // col 33, rows 1..32
        pb[pl * 1156 + idx] = 0.f;
    }
    int y = t >> 5, x = t & 31;
    #pragma unroll
    for (int r = 0; r < 16; ++r) {
        float val = (src[t + (r << 10)] - mu) * rs * gw[g * 16 + r] + gb[g * 16 + r];
        pb[r * 1156 + (y + 1) * 34 + (x + 1)] = val;
    }
}

// ---------------------------------------------------------------------------
// 3x3 SAME convs, LDS-staged, 4 output channels per block, float4 staging.
// ---------------------------------------------------------------------------
__global__ __launch_bounds__(256) void conv_kernel(const float* __restrict__ up,
                                                   const float* __restrict__ wd,
                                                   const float* __restrict__ bd,
                                                   const float* __restrict__ wB,
                                                   const float* __restrict__ wC,
                                                   const float* __restrict__ dtb,
                                                   float* __restrict__ delta,
                                                   float* __restrict__ Bv,
                                                   float* __restrict__ Cv)
{
    __shared__ float sin_[64 * 204];   // 64 ci x 6 rows x 34 cols = 52224 B
    int blk = blockIdx.x;              // b*192 + og*8 + strip
    int strip = blk & 7;
    int og = (blk >> 3) % 24;
    int b = blk / 192;
    int h0 = strip * 4;
    int t = threadIdx.x;

    const float4* plane4 = (const float4*)(up + (size_t)b * 73984 + h0 * 34);
    float4* s4 = (float4*)sin_;
    #pragma unroll
    for (int k = 0; k < 13; ++k) {
        int i4 = t + (k << 8);
        if (i4 < 3264) {
            int ci = i4 / 51, r4 = i4 - ci * 51;
            s4[i4] = plane4[ci * 289 + r4];
        }
    }
    __syncthreads();

    int o0 = og * 4;
    const float* wsel;
    if (o0 < 64)      wsel = wd + (size_t)o0 * 576;
    else if (o0 < 80) wsel = wB + (size_t)(o0 - 64) * 576;
    else              wsel = wC + (size_t)(o0 - 80) * 576;

    int half = t >> 7;
    int px = t & 127;
    int r = px >> 5, c = px & 31;
    const float* base = sin_ + r * 34 + c;

    float acc0 = 0.f, acc1 = 0.f, acc2 = 0.f, acc3 = 0.f;
    int ci0 = half * 32;
    for (int ci = ci0; ci < ci0 + 32; ++ci) {
        const float* pp = base + ci * 204;
        const float* wp = wsel + ci * 9;
        #pragma unroll
        for (int dy = 0; dy < 3; ++dy)
            #pragma unroll
            for (int dx = 0; dx < 3; ++dx) {
                float v = pp[dy * 34 + dx];
                int wi = dy * 3 + dx;
                acc0 += v * wp[wi];
                acc1 += v * wp[576 + wi];
                acc2 += v * wp[1152 + wi];
                acc3 += v * wp[1728 + wi];
            }
    }
    __syncthreads();
    float4* red4 = (float4*)sin_;
    red4[t] = make_float4(acc0, acc1, acc2, acc3);
    __syncthreads();
    if (t < 128) {
        float4 a = red4[t], bq = red4[t + 128];
        float s[4] = {a.x + bq.x, a.y + bq.y, a.z + bq.z, a.w + bq.w};
        int pidx = (h0 + r) * 32 + c;
        if (o0 < 64) {
            #pragma unroll
            for (int k = 0; k < 4; ++k) {
                float x = s[k] + bd[o0 + k] + dtb[0];
                float sp = (x > 20.f) ? x : log1pf(expf(x));
                sp = fminf(fmaxf(sp, 1e-4f), 5.f);
                delta[((size_t)(b * 64 + o0 + k) << 10) + pidx] = sp;
            }
        } else if (o0 < 80) {
            #pragma unroll
            for (int k = 0; k < 4; ++k)
                Bv[((size_t)(b * 16 + o0 - 64 + k) << 10) + pidx] = s[k];
        } else {
            #pragma unroll
            for (int k = 0; k < 4; ++k)
                Cv[((size_t)(b * 16 + o0 - 80 + k) << 10) + pidx] = s[k];
        }
    }
}

// ---------------------------------------------------------------------------
// Main fused kernel, v-specialized. 2048 blocks = (b, v, d), 16 n/block.
// AXIS ROTATIONS ARE EXACT PIXEL PERMUTATIONS (wx=wy=0 bitwise, since ix is
// an exactly-representable integer -> bilinear weights collapse to {1,0,0,0}):
//   v=0: out(y,x)=in(y,x)        -> pure stream, NO LDS, NO barriers
//   v=4: out(y,x)=in(31-y,31-x)  -> reversed coalesced float4, NO LDS
//   v=2: out(y,x)=in(31-x,y)     -> LDS single-tap, stride-33 planes
//   v=6: out(y,x)=in(x,31-y)     -> LDS single-tap, stride-33 planes
//   odd v: round-5 bilinear path (4 taps, stride-35 + guard), unchanged.
// This is the differential probe for "per-wave work vs memory-system wall":
// even-v blocks shed 75-100% of their LDS/weight work; if fused time doesn't
// move, the 2.5 TB/s rate is the memory system and we are at the roofline.
// ---------------------------------------------------------------------------
__global__ __launch_bounds__(256) void fused_state_kernel(
    const float* __restrict__ s_prev, const float* __restrict__ u_t,
    const float* __restrict__ delta, const float* __restrict__ Bv,
    const float* __restrict__ Cv, const float* __restrict__ logA,
    const float* __restrict__ Dp, float* __restrict__ y_out,
    float* __restrict__ s_out)
{
    __shared__ float lds[4 * 1190];   // 19040 B (odd path; even-D uses 4*1056)
    __shared__ float Ash[16];
    int blk = blockIdx.x;             // b*512 + v*64 + d
    int d = blk & 63, v = (blk >> 6) & 7, b = blk >> 9;
    int t = threadIdx.x;

    if (t < 16) Ash[t] = -__expf(logA[d * 16 + t]);

    size_t so_base = ((size_t)((b * 8 + v) * 64 + d)) << 14;  // 16384 floats
    const f4* src4 = (const f4*)(s_prev + so_base);
    const f4* dpl4 = (const f4*)(delta + ((size_t)(b * 64 + d) << 10));
    const f4* upl4 = (const f4*)(u_t   + ((size_t)(b * 64 + d) << 10));
    const f4* bvb  = (const f4*)(Bv + ((size_t)b << 14));
    const f4* cvb  = (const f4*)(Cv + ((size_t)b << 14));
    f4* soc4 = (f4*)(s_out + so_base);
    float Dd = Dp[d];

    f4 dd4 = dpl4[t], uv4 = upl4[t];
    int h = t >> 3, x0 = (t & 7) << 2;   // pixel group: p = 4t..4t+3
    f4 duv, yacc;
    #pragma unroll
    for (int j = 0; j < 4; ++j) { duv[j] = dd4[j] * uv4[j]; yacc[j] = 0.f; }

    if (v == 0) {
        // ---- identity transport: pure stream ----
        __syncthreads();               // Ash ready
        #pragma unroll 4
        for (int pl = 0; pl < 16; ++pl) {
            int idx = (pl << 8) + t;
            f4 sp = src4[idx];
            f4 B4 = bvb[idx], C4 = cvb[idx];
            float An = Ash[pl];
            f4 sn4;
            #pragma unroll
            for (int j = 0; j < 4; ++j) {
                float sn = __expf(dd4[j] * An) * sp[j] + duv[j] * B4[j];
                sn4[j] = sn; yacc[j] += sn * C4[j];
            }
            soc4[idx] = sn4;
        }
    } else if (v == 4) {
        // ---- 180 deg: in(31-h, 31-x), reversed float4 + component swap ----
        __syncthreads();               // Ash ready
        int tin = ((31 - h) << 3) + (7 - (t & 7));
        #pragma unroll 4
        for (int pl = 0; pl < 16; ++pl) {
            int idx = (pl << 8) + t;
            f4 sp = src4[(pl << 8) + tin];
            f4 B4 = bvb[idx], C4 = cvb[idx];
            float An = Ash[pl];
            f4 sn4;
            #pragma unroll
            for (int j = 0; j < 4; ++j) {
                float sn = __expf(dd4[j] * An) * sp[3 - j] + duv[j] * B4[j];
                sn4[j] = sn; yacc[j] += sn * C4[j];
            }
            soc4[idx] = sn4;
        }
    } else if (!(v & 1)) {
        // ---- 90/270 deg: single-tap via stride-33 LDS planes ----
        int pb2 = (31 - x0) * 33 + h;        // v==2: in(31-x, h), j step -33
        int pb6 = x0 * 33 + (31 - h);        // v==6: in(x, 31-h), j step +33
        #pragma unroll 1
        for (int c = 0; c < 4; ++c) {
            if (c) __syncthreads();
            const float4* srcc = (const float4*)(s_prev + so_base + ((size_t)c << 12));
            #pragma unroll
            for (int k = 0; k < 4; ++k) {
                int q = t + (k << 8);
                float4 val = srcc[q];
                int lin = q << 2;
                int nn = lin >> 10, rem = lin & 1023;
                int di = nn * 1056 + ((rem >> 5) * 33) + (rem & 31);
                lds[di] = val.x; lds[di + 1] = val.y; lds[di + 2] = val.z; lds[di + 3] = val.w;
            }
            __syncthreads();
            #pragma unroll
            for (int nn = 0; nn < 4; ++nn) {
                int idx = (((c << 2) + nn) << 8) + t;
                f4 B4 = bvb[idx], C4 = cvb[idx];
                float An = Ash[(c << 2) + nn];
                f4 sn4;
                if (v == 2) {
                    #pragma unroll
                    for (int j = 0; j < 4; ++j) {
                        float sp = lds[nn * 1056 + pb2 - j * 33];
                        float sn = __expf(dd4[j] * An) * sp + duv[j] * B4[j];
                        sn4[j] = sn; yacc[j] += sn * C4[j];
                    }
                } else {
                    #pragma unroll
                    for (int j = 0; j < 4; ++j) {
                        float sp = lds[nn * 1056 + pb6 + j * 33];
                        float sn = __expf(dd4[j] * An) * sp + duv[j] * B4[j];
                        sn4[j] = sn; yacc[j] += sn * C4[j];
                    }
                }
                soc4[idx] = sn4;
            }
        }
    } else {
        // ---- odd v: bilinear path (round-5 structure, measured 85.6 us) ----
        for (int k = t; k < 528; k += 256) {
            int pl = k / 132, g = k - pl * 132;
            int idx;
            if (g < 34)       idx = g;                   // row 0
            else if (g < 68)  idx = 33 * 35 + (g - 34);  // row 33
            else if (g < 100) idx = (g - 67) * 35;       // col 0, rows 1..32
            else              idx = (g - 99) * 35 + 33;  // col 33, rows 1..32
            lds[pl * 1190 + idx] = 0.f;
        }
        const float cc = CTAB[v], ss = STAB[v];
        float Yc = (h + 0.5f) * 0.0625f - 1.f;
        float w00[4], w01[4], w10[4], w11[4];
        int tb[4];
        #pragma unroll
        for (int j = 0; j < 4; ++j) {
            int wpx = x0 | j;
            float X = (wpx + 0.5f) * 0.0625f - 1.f;
            float gx = cc * X - ss * Yc;
            float gy = ss * X + cc * Yc;
            float ix = (gx + 1.f) * 16.f - 0.5f;
            float iy = (gy + 1.f) * 16.f - 0.5f;
            float fx0 = floorf(ix), fy0 = floorf(iy);
            float wx = ix - fx0, wy = iy - fy0;
            int xx0 = (int)fx0, yy0 = (int)fy0;
            float mx0 = (xx0 >= 0 && xx0 < 32) ? (1.f - wx) : 0.f;
            float mx1 = (xx0 >= -1 && xx0 < 31) ? wx : 0.f;
            float my0 = (yy0 >= 0 && yy0 < 32) ? (1.f - wy) : 0.f;
            float my1 = (yy0 >= -1 && yy0 < 31) ? wy : 0.f;
            w00[j] = my0 * mx0; w01[j] = my0 * mx1;
            w10[j] = my1 * mx0; w11[j] = my1 * mx1;
            int bx = min(max(xx0, -1), 31), by = min(max(yy0, -1), 31);
            tb[j] = (by + 1) * 35 + (bx + 1);   // taps: +0,+1,+35,+36
        }
        #pragma unroll 1
        for (int c = 0; c < 4; ++c) {
            if (c) __syncthreads();
            const float4* srcc = (const float4*)(s_prev + so_base + ((size_t)c << 12));
            #pragma unroll
            for (int k = 0; k < 4; ++k) {
                int q = t + (k << 8);
                float4 val = srcc[q];
                int lin = q << 2;
                int nn = lin >> 10, rem = lin & 1023;
                int di = nn * 1190 + ((rem >> 5) + 1) * 35 + (rem & 31) + 1;
                lds[di] = val.x; lds[di + 1] = val.y; lds[di + 2] = val.z; lds[di + 3] = val.w;
            }
            __syncthreads();
            #pragma unroll
            for (int nn = 0; nn < 4; ++nn) {
                int idx = (((c << 2) + nn) << 8) + t;
                f4 B4 = bvb[idx], C4 = cvb[idx];
                float An = Ash[(c << 2) + nn];
                f4 sn4;
                #pragma unroll
                for (int j = 0; j < 4; ++j) {
                    int si = tb[j] + nn * 1190;
                    float bil = lds[si] * w00[j] + lds[si + 1] * w01[j]
                              + lds[si + 35] * w10[j] + lds[si + 36] * w11[j];
                    float sn = __expf(dd4[j] * An) * bil + duv[j] * B4[j];
                    sn4[j] = sn; yacc[j] += sn * C4[j];
                }
                soc4[idx] = sn4;
            }
        }
    }

    // single vectorized y store — no atomics, no pre-zero
    f4 y4;
    #pragma unroll
    for (int j = 0; j < 4; ++j) y4[j] = yacc[j] + uv4[j] * Dd;
    f4* yo4 = (f4*)(y_out + (((size_t)((b * 8 + v) * 64 + d)) << 10));
    yo4[t] = y4;
}

// ---------------------------------------------------------------------------
extern "C" void kernel_launch(void* const* d_in, const int* in_sizes, int n_in,
                              void* d_out, int out_size, void* d_ws, size_t ws_size,
                              hipStream_t stream)
{
    const float* u_t    = (const float*)d_in[0];
    const float* s_prev = (const float*)d_in[1];
    const float* gn_w   = (const float*)d_in[2];
    const float* gn_b   = (const float*)d_in[3];
    const float* wd     = (const float*)d_in[4];
    const float* bd     = (const float*)d_in[5];
    const float* wB     = (const float*)d_in[6];
    const float* wC     = (const float*)d_in[7];
    const float* logA   = (const float*)d_in[8];
    const float* Dp     = (const float*)d_in[9];
    const float* dtb    = (const float*)d_in[10];

    float* y_out = (float*)d_out;            // (4,8,64,32,32) = 2097152 floats
    float* s_out = y_out + 2097152;          // (4,8,64,16,32,32) = 33554432 floats

    float* up    = (float*)d_ws;             // padded u_norm: 4*64*1156 = 295936
    float* delta = up + 295936;              // 4*64*1024 = 262144
    float* Bv    = delta + 262144;           // 4*16*1024 = 65536
    float* Cv    = Bv + 65536;               // 65536

    hipLaunchKernelGGL(gn_kernel, dim3(16), dim3(1024), 0, stream, u_t, gn_w, gn_b, up);
    hipLaunchKernelGGL(conv_kernel, dim3(768), dim3(256), 0, stream,
                       up, wd, bd, wB, wC, dtb, delta, Bv, Cv);
    hipLaunchKernelGGL(fused_state_kernel, dim3(2048), dim3(256), 0, stream,
                       s_prev, u_t, delta, Bv, Cv, logA, Dp, y_out, s_out);
}

// Round 8
// 300.975 us; speedup vs baseline: 1.0598x; 1.0598x over previous
//
#include <hip/hip_runtime.h>
#include <cmath>

// Shapes: B=4, V=8, D=64, N=16, H=32, W=32, GROUPS=4
// rotation tables: a = radians(-45*v); c = cos(a), s = sin(a)
#define FSQ 0.70710678118654752440f
__constant__ float CTAB[8] = {1.f,  FSQ, 0.f, -FSQ, -1.f, -FSQ, 0.f, FSQ};
__constant__ float STAB[8] = {0.f, -FSQ, -1.f, -FSQ,  0.f,  FSQ, 1.f, FSQ};

typedef float f4 __attribute__((ext_vector_type(4)));

// ---------------------------------------------------------------------------
// GroupNorm: 16 blocks = (b, group), 1024 threads. Wave-shuffle reduction.
// Writes u_norm into zero-padded (34x34) planes in ws.
// ---------------------------------------------------------------------------
__global__ __launch_bounds__(1024) void gn_kernel(const float* __restrict__ u,
                                                  const float* __restrict__ gw,
                                                  const float* __restrict__ gb,
                                                  float* __restrict__ up)
{
    int blk = blockIdx.x;            // b*4 + g
    int b = blk >> 2, g = blk & 3;
    int t = threadIdx.x;
    const float* src = u + ((size_t)(b * 64 + g * 16) << 10);   // 16384 floats
    float sum = 0.f, sq = 0.f;
    #pragma unroll
    for (int r = 0; r < 16; ++r) {
        float v = src[t + (r << 10)];
        sum += v; sq += v * v;
    }
    #pragma unroll
    for (int ofs = 32; ofs > 0; ofs >>= 1) {
        sum += __shfl_down(sum, ofs);
        sq  += __shfl_down(sq, ofs);
    }
    __shared__ float red[16], red2[16];
    int wv = t >> 6;
    if ((t & 63) == 0) { red[wv] = sum; red2[wv] = sq; }
    __syncthreads();
    float s_tot = 0.f, q_tot = 0.f;
    #pragma unroll
    for (int k = 0; k < 16; ++k) { s_tot += red[k]; q_tot += red2[k]; }
    float mu  = s_tot * (1.f / 16384.f);
    float var = q_tot * (1.f / 16384.f) - mu * mu;
    float rs  = rsqrtf(var + 1e-5f);

    float* pb = up + (size_t)(b * 64 + g * 16) * 1156;
    for (int k = t; k < 16 * 132; k += 1024) {
        int pl = k / 132, c = k - pl * 132;
        int idx;
        if (c < 34)       idx = c;                       // row 0
        else if (c < 68)  idx = 33 * 34 + (c - 34);      // row 33
        else if (c < 100) idx = (c - 68 + 1) * 34;       // col 0, rows 1..32
        else              idx = (c - 100 + 1) * 34 + 33; // col 33, rows 1..32
        pb[pl * 1156 + idx] = 0.f;
    }
    int y = t >> 5, x = t & 31;
    #pragma unroll
    for (int r = 0; r < 16; ++r) {
        float val = (src[t + (r << 10)] - mu) * rs * gw[g * 16 + r] + gb[g * 16 + r];
        pb[r * 1156 + (y + 1) * 34 + (x + 1)] = val;
    }
}

// ---------------------------------------------------------------------------
// 3x3 SAME convs, LDS-staged, 4 output channels per block, float4 staging.
// ---------------------------------------------------------------------------
__global__ __launch_bounds__(256) void conv_kernel(const float* __restrict__ up,
                                                   const float* __restrict__ wd,
                                                   const float* __restrict__ bd,
                                                   const float* __restrict__ wB,
                                                   const float* __restrict__ wC,
                                                   const float* __restrict__ dtb,
                                                   float* __restrict__ delta,
                                                   float* __restrict__ Bv,
                                                   float* __restrict__ Cv)
{
    __shared__ float sin_[64 * 204];   // 64 ci x 6 rows x 34 cols = 52224 B
    int blk = blockIdx.x;              // b*192 + og*8 + strip
    int strip = blk & 7;
    int og = (blk >> 3) % 24;
    int b = blk / 192;
    int h0 = strip * 4;
    int t = threadIdx.x;

    const float4* plane4 = (const float4*)(up + (size_t)b * 73984 + h0 * 34);
    float4* s4 = (float4*)sin_;
    #pragma unroll
    for (int k = 0; k < 13; ++k) {
        int i4 = t + (k << 8);
        if (i4 < 3264) {
            int ci = i4 / 51, r4 = i4 - ci * 51;
            s4[i4] = plane4[ci * 289 + r4];
        }
    }
    __syncthreads();

    int o0 = og * 4;
    const float* wsel;
    if (o0 < 64)      wsel = wd + (size_t)o0 * 576;
    else if (o0 < 80) wsel = wB + (size_t)(o0 - 64) * 576;
    else              wsel = wC + (size_t)(o0 - 80) * 576;

    int half = t >> 7;
    int px = t & 127;
    int r = px >> 5, c = px & 31;
    const float* base = sin_ + r * 34 + c;

    float acc0 = 0.f, acc1 = 0.f, acc2 = 0.f, acc3 = 0.f;
    int ci0 = half * 32;
    for (int ci = ci0; ci < ci0 + 32; ++ci) {
        const float* pp = base + ci * 204;
        const float* wp = wsel + ci * 9;
        #pragma unroll
        for (int dy = 0; dy < 3; ++dy)
            #pragma unroll
            for (int dx = 0; dx < 3; ++dx) {
                float v = pp[dy * 34 + dx];
                int wi = dy * 3 + dx;
                acc0 += v * wp[wi];
                acc1 += v * wp[576 + wi];
                acc2 += v * wp[1152 + wi];
                acc3 += v * wp[1728 + wi];
            }
    }
    __syncthreads();
    float4* red4 = (float4*)sin_;
    red4[t] = make_float4(acc0, acc1, acc2, acc3);
    __syncthreads();
    if (t < 128) {
        float4 a = red4[t], bq = red4[t + 128];
        float s[4] = {a.x + bq.x, a.y + bq.y, a.z + bq.z, a.w + bq.w};
        int pidx = (h0 + r) * 32 + c;
        if (o0 < 64) {
            #pragma unroll
            for (int k = 0; k < 4; ++k) {
                float x = s[k] + bd[o0 + k] + dtb[0];
                float sp = (x > 20.f) ? x : log1pf(expf(x));
                sp = fminf(fmaxf(sp, 1e-4f), 5.f);
                delta[((size_t)(b * 64 + o0 + k) << 10) + pidx] = sp;
            }
        } else if (o0 < 80) {
            #pragma unroll
            for (int k = 0; k < 4; ++k)
                Bv[((size_t)(b * 16 + o0 - 64 + k) << 10) + pidx] = s[k];
        } else {
            #pragma unroll
            for (int k = 0; k < 4; ++k)
                Cv[((size_t)(b * 16 + o0 - 80 + k) << 10) + pidx] = s[k];
        }
    }
}

// ---------------------------------------------------------------------------
// Main fused kernel (R6 structure + burst-coherence edits): 2048 blocks =
// (b,v,d); 16 n via 4 phases over DOUBLE-BUFFERED LDS (38 KB), T14
// issue-early/write-late prefetch, ONE barrier per phase.
// Burst-coherence edits (stream-thrash hypothesis — the only model fitting
// all 8 prior data points: every structure lands at 2.2-2.6 TB/s combined
// R+W while no CU pipe exceeds ~40%):
//  1. All 8 B/C loads of a phase issued back-to-back (16 KB/block bursts
//     per stream instead of 8 interleaved 4 KB granules). Indexing is
//     compile-time (full unroll) — no rule-#20 scratch.
//  2. s_out and y_out stores nontemporal: 139 MB write-once traffic
//     bypasses L2, keeping B/C/delta/u resident and giving the memory
//     controller a clean write stream.
// LDS row stride 35; guard zeroed once; no atomics/memset.
// ---------------------------------------------------------------------------
__global__ __launch_bounds__(256) void fused_state_kernel(
    const float* __restrict__ s_prev, const float* __restrict__ u_t,
    const float* __restrict__ delta, const float* __restrict__ Bv,
    const float* __restrict__ Cv, const float* __restrict__ logA,
    const float* __restrict__ Dp, float* __restrict__ y_out,
    float* __restrict__ s_out)
{
    __shared__ float lds[2 * 4 * 1190];   // 38080 B
    __shared__ float Ash[16];
    int blk = blockIdx.x;             // b*512 + v*64 + d
    int d = blk & 63, v = (blk >> 6) & 7, b = blk >> 9;
    int t = threadIdx.x;

    if (t < 16) Ash[t] = -__expf(logA[d * 16 + t]);
    // zero guard cells of ALL 8 planes (both buffers) once
    for (int k = t; k < 1056; k += 256) {
        int pl = k / 132, g = k - pl * 132;
        int idx;
        if (g < 34)       idx = g;                   // row 0
        else if (g < 68)  idx = 33 * 35 + (g - 34);  // row 33
        else if (g < 100) idx = (g - 67) * 35;       // col 0, rows 1..32
        else              idx = (g - 99) * 35 + 33;  // col 33, rows 1..32
        lds[pl * 1190 + idx] = 0.f;
    }

    size_t so_base = ((size_t)((b * 8 + v) * 64 + d)) << 14;  // 16384 floats
    const float4* src = (const float4*)(s_prev + so_base);

// scatter one float4 (chunk-local f4 index q) into LDS buffer at base nb
#define DSW(nb, q, val) { int lin = (q) << 2; int nn = lin >> 10; int rem = lin & 1023; \
    int di = (nb) + nn * 1190 + ((rem >> 5) + 1) * 35 + (rem & 31) + 1; \
    lds[di] = (val).x; lds[di + 1] = (val).y; lds[di + 2] = (val).z; lds[di + 3] = (val).w; }

    // prologue: stage chunk 0 into buf0
    {
        float4 a0 = src[t], a1 = src[t + 256], a2 = src[t + 512], a3 = src[t + 768];
        DSW(0, t, a0); DSW(0, t + 256, a1); DSW(0, t + 512, a2); DSW(0, t + 768, a3);
    }

    const float cc = CTAB[v], ss = STAB[v];
    const f4* dpl4 = (const f4*)(delta + ((size_t)(b * 64 + d) << 10));
    const f4* upl4 = (const f4*)(u_t   + ((size_t)(b * 64 + d) << 10));
    float Dd = Dp[d];

    f4 dd4 = dpl4[t], uv4 = upl4[t];

    // pixel group: p = 4t..4t+3 -> h = t>>3 (wave-uniform rows), wpx = 4*(t&7)+j
    int h = t >> 3;
    float Yc = (h + 0.5f) * 0.0625f - 1.f;
    float w00[4], w01[4], w10[4], w11[4], duv[4], yacc[4];
    int tb[4];
    #pragma unroll
    for (int j = 0; j < 4; ++j) {
        int wpx = ((t & 7) << 2) | j;
        float X = (wpx + 0.5f) * 0.0625f - 1.f;
        float gx = cc * X - ss * Yc;
        float gy = ss * X + cc * Yc;
        float ix = (gx + 1.f) * 16.f - 0.5f;
        float iy = (gy + 1.f) * 16.f - 0.5f;
        float fx0 = floorf(ix), fy0 = floorf(iy);
        float wx = ix - fx0, wy = iy - fy0;
        int x0 = (int)fx0, y0 = (int)fy0;
        float mx0 = (x0 >= 0 && x0 < 32) ? (1.f - wx) : 0.f;
        float mx1 = (x0 >= -1 && x0 < 31) ? wx : 0.f;
        float my0 = (y0 >= 0 && y0 < 32) ? (1.f - wy) : 0.f;
        float my1 = (y0 >= -1 && y0 < 31) ? wy : 0.f;
        w00[j] = my0 * mx0; w01[j] = my0 * mx1;
        w10[j] = my1 * mx0; w11[j] = my1 * mx1;
        int bx = min(max(x0, -1), 31), by = min(max(y0, -1), 31);
        tb[j] = (by + 1) * 35 + (bx + 1);   // taps: +0,+1,+35,+36 (guard zeroed)
        duv[j] = dd4[j] * uv4[j];
        yacc[j] = 0.f;
    }
    __syncthreads();                   // buf0 staged + guards zeroed

    #pragma unroll 1                   // do NOT let the compiler hoist all prefetches
    for (int c = 0; c < 4; ++c) {
        int cb = (c & 1) * 4760;       // current buffer base
        // issue next chunk's loads BEFORE compute (in flight under it)
        float4 r0, r1, r2, r3;
        if (c < 3) {
            int o = (c + 1) << 10;
            r0 = src[o + t];       r1 = src[o + t + 256];
            r2 = src[o + t + 512]; r3 = src[o + t + 768];
            asm volatile("" ::: "memory");   // pin issue point
        }

        // burst-load the phase's B and C streams back-to-back (8 dwordx4)
        const f4* bvc4 = (const f4*)(Bv + ((size_t)b << 14) + (c << 12));
        const f4* cvc4 = (const f4*)(Cv + ((size_t)b << 14) + (c << 12));
        f4 Bq[4], Cq[4];
        #pragma unroll
        for (int nn = 0; nn < 4; ++nn) Bq[nn] = bvc4[(nn << 8) + t];
        #pragma unroll
        for (int nn = 0; nn < 4; ++nn) Cq[nn] = cvc4[(nn << 8) + t];

        f4* soc4 = (f4*)(s_out + so_base + ((size_t)c << 12));
        #pragma unroll
        for (int nn = 0; nn < 4; ++nn) {
            float An = Ash[(c << 2) + nn];
            f4 sn4;
            #pragma unroll
            for (int j = 0; j < 4; ++j) {
                int si = cb + tb[j] + nn * 1190;
                float bil = lds[si] * w00[j] + lds[si + 1] * w01[j]
                          + lds[si + 35] * w10[j] + lds[si + 36] * w11[j];
                float abar = __expf(dd4[j] * An);
                float sn = abar * bil + duv[j] * Bq[nn][j];
                sn4[j] = sn;
                yacc[j] += sn * Cq[nn][j];
            }
            __builtin_nontemporal_store(sn4, soc4 + (nn << 8) + t);
        }

        // write prefetched chunk into the OTHER buffer (nobody reads it now)
        if (c < 3) {
            int nb = cb ^ 4760;
            DSW(nb, t, r0); DSW(nb, t + 256, r1);
            DSW(nb, t + 512, r2); DSW(nb, t + 768, r3);
        }
        __syncthreads();               // single barrier per phase
    }
#undef DSW

    // single vectorized y store — no atomics, no pre-zero
    f4 y4;
    #pragma unroll
    for (int j = 0; j < 4; ++j) y4[j] = yacc[j] + uv4[j] * Dd;
    f4* yo4 = (f4*)(y_out + (((size_t)((b * 8 + v) * 64 + d)) << 10));
    __builtin_nontemporal_store(y4, yo4 + t);
}

// ---------------------------------------------------------------------------
extern "C" void kernel_launch(void* const* d_in, const int* in_sizes, int n_in,
                              void* d_out, int out_size, void* d_ws, size_t ws_size,
                              hipStream_t stream)
{
    const float* u_t    = (const float*)d_in[0];
    const float* s_prev = (const float*)d_in[1];
    const float* gn_w   = (const float*)d_in[2];
    const float* gn_b   = (const float*)d_in[3];
    const float* wd     = (const float*)d_in[4];
    const float* bd     = (const float*)d_in[5];
    const float* wB     = (const float*)d_in[6];
    const float* wC     = (const float*)d_in[7];
    const float* logA   = (const float*)d_in[8];
    const float* Dp     = (const float*)d_in[9];
    const float* dtb    = (const float*)d_in[10];

    float* y_out = (float*)d_out;            // (4,8,64,32,32) = 2097152 floats
    float* s_out = y_out + 2097152;          // (4,8,64,16,32,32) = 33554432 floats

    float* up    = (float*)d_ws;             // padded u_norm: 4*64*1156 = 295936
    float* delta = up + 295936;              // 4*64*1024 = 262144
    float* Bv    = delta + 262144;           // 4*16*1024 = 65536
    float* Cv    = Bv + 65536;               // 65536

    hipLaunchKernelGGL(gn_kernel, dim3(16), dim3(1024), 0, stream, u_t, gn_w, gn_b, up);
    hipLaunchKernelGGL(conv_kernel, dim3(768), dim3(256), 0, stream,
                       up, wd, bd, wB, wC, dtb, delta, Bv, Cv);
    hipLaunchKernelGGL(fused_state_kernel, dim3(2048), dim3(256), 0, stream,
                       s_prev, u_t, delta, Bv, Cv, logA, Dp, y_out, s_out);
}